// Round 10
// baseline (190.135 us; speedup 1.0000x reference)
//
#include <hip/hip_runtime.h>
#include <math.h>

#define NTOK 16384
#define DK   2048
#define NEXP 64

typedef float f32x4 __attribute__((ext_vector_type(4)));
typedef int   i32x4 __attribute__((ext_vector_type(4)));
typedef short s16x8 __attribute__((ext_vector_type(8)));

// ---- scalar RTNE fp32->bf16 (pre-kernel only) ----
__device__ __forceinline__ unsigned short f2bf(float f) {
    union { float f; unsigned u; } v; v.f = f;
    unsigned r = (v.u + 0x7FFFu + ((v.u >> 16) & 1u)) >> 16;
    return (unsigned short)r;
}
__device__ __forceinline__ float bf2f(unsigned short h) {
    union { unsigned u; float f; } v; v.u = ((unsigned)h) << 16;
    return v.f;
}

// Pre-kernel: exact 3-way bf16 split of W into d_ws planes [3][64][2048].
__global__ __launch_bounds__(256) void wsplit_kernel(const float* __restrict__ Wg,
                                                     unsigned short* __restrict__ ws) {
    const int i = blockIdx.x * 256 + threadIdx.x;    // 131072 elems, grid 512
    const float f = Wg[i];
    const unsigned short h0 = f2bf(f);  const float r1 = f - bf2f(h0);
    const unsigned short h1 = f2bf(r1); const float r2 = r1 - bf2f(h1);
    const unsigned short h2 = f2bf(r2);
    ws[i] = h0; ws[131072 + i] = h1; ws[262144 + i] = h2;
}

// packed fp32->bf16x2 (RTNE), result u32 = [f0 in lo16 | f1 in hi16]
__device__ __forceinline__ unsigned cvtpk(float lo, float hi) {
    unsigned r;
    asm("v_cvt_pk_bf16_f32 %0, %1, %2" : "=v"(r) : "v"(lo), "v"(hi));
    return r;
}

// 3-way split of a float pair straight into the A-fragment u32s.
#define SPLIT2(F0, F1, O0, O1, O2) { \
    const unsigned q0 = cvtpk((F0), (F1)); \
    const float s0 = (F0) - __builtin_bit_cast(float, q0 << 16); \
    const float s1 = (F1) - __builtin_bit_cast(float, q0 & 0xFFFF0000u); \
    const unsigned q1 = cvtpk(s0, s1); \
    const float t0 = s0 - __builtin_bit_cast(float, q1 << 16); \
    const float t1 = s1 - __builtin_bit_cast(float, q1 & 0xFFFF0000u); \
    O0 = (int)q0; O1 = (int)q1; O2 = (int)cvtpk(t0, t1); }

// Issue round-c loads. Per round: 2 x-float4 + 12 B-i32x4 = 14 VMEM (vmcnt unit).
#define ISSUE_X(XS, c) { \
    _Pragma("unroll") for (int h = 0; h < 2; ++h) \
        XS[h] = *(const float4*)(xbase + h * 4 + (c) * 32); }

#define ISSUE_B(BS, c) { \
    _Pragma("unroll") for (int n = 0; n < 4; ++n) \
        _Pragma("unroll") for (int p = 0; p < 3; ++p) \
            BS[n][p] = *(const i32x4*)(wsbase + (size_t)p * 131072 + n * 32768 + (c) * 32); }

// Convert landed x fp32 (8 elems/lane) into 3 A-plane frags.
#define CONV(XS) { \
    SPLIT2(XS[0].x, XS[0].y, A[0].x, A[1].x, A[2].x); \
    SPLIT2(XS[0].z, XS[0].w, A[0].y, A[1].y, A[2].y); \
    SPLIT2(XS[1].x, XS[1].y, A[0].z, A[1].z, A[2].z); \
    SPLIT2(XS[1].z, XS[1].w, A[0].w, A[1].w, A[2].w); }

#define MFMA_TERM(pa, pb, BS) { \
    _Pragma("unroll") for (int n = 0; n < 4; ++n) \
        acc[n] = __builtin_amdgcn_mfma_f32_16x16x32_bf16( \
            __builtin_bit_cast(s16x8, A[pa]), \
            __builtin_bit_cast(s16x8, BS[n][pb]), acc[n], 0, 0, 0); }

// 6 terms cover the product to ~2^-27: (0,0),(0,1),(1,0),(1,1),(0,2),(2,0)
#define MFMA_ALL(BS) \
    MFMA_TERM(0, 0, BS) MFMA_TERM(0, 1, BS) MFMA_TERM(1, 0, BS) \
    MFMA_TERM(1, 1, BS) MFMA_TERM(0, 2, BS) MFMA_TERM(2, 0, BS)

// Steady phase: at entry 28 VMEM outstanding (rounds c, c+1); vmcnt(14) lands c.
#define PHASE_MAIN(XS, BS, c) { \
    asm volatile("s_waitcnt vmcnt(14)" ::: "memory"); \
    __builtin_amdgcn_sched_barrier(0); \
    CONV(XS); \
    ISSUE_X(XS, (c) + 2); \
    MFMA_ALL(BS); \
    ISSUE_B(BS, (c) + 2); \
    __builtin_amdgcn_sched_barrier(0); }

__global__ __launch_bounds__(256, 4) void topk_router_kernel(
    const float* __restrict__ x,            // [NTOK][DK] fp32
    const unsigned short* __restrict__ ws,  // [3][64][2048] bf16 W planes
    float* __restrict__ out)                // [NTOK*2] idx (as float) ++ [NTOK*2] w
{
    __shared__ float lg[4][16][68];         // per-K-quarter partial logits

    const int tid  = threadIdx.x;
    const int w    = tid >> 6;              // wave 0..3 == K-quarter
    const int lane = tid & 63;
    const int rr   = lane & 15;             // frag row/col index
    const int g    = lane >> 4;             // frag k-group (8 k each)
    const int tok0 = blockIdx.x * 16;

    // A-source: x[tok0+rr][w*512 + 32c + g*8 + 4h]  (frag-layout-direct)
    const float* xbase = x + (size_t)(tok0 + rr) * DK + w * 512 + g * 8;
    // B-source: ws plane p, row = 16n+rr (expert), same k slice (L1/L2-resident)
    const unsigned short* wsbase = ws + (size_t)rr * DK + w * 512 + g * 8;

    f32x4 acc[4];
    #pragma unroll
    for (int n = 0; n < 4; ++n) acc[n] = (f32x4){0.f, 0.f, 0.f, 0.f};

    float4 X0[2], X1[2];
    i32x4  B0[4][3], B1[4][3];
    i32x4  A[3];

    // ---- prologue: rounds 0,1 in flight (14 VMEM each) ----
    ISSUE_X(X0, 0); ISSUE_B(B0, 0);
    ISSUE_X(X1, 1); ISSUE_B(B1, 1);

    // ---- main loop: 16 K32-rounds per wave, no barriers, no LDS ----
    #pragma unroll 1
    for (int c = 0; c < 14; c += 2) {
        PHASE_MAIN(X0, B0, c);
        PHASE_MAIN(X1, B1, c + 1);
    }
    // tail rounds 14, 15
    asm volatile("s_waitcnt vmcnt(14)" ::: "memory");
    __builtin_amdgcn_sched_barrier(0);
    CONV(X0); MFMA_ALL(B0);
    asm volatile("s_waitcnt vmcnt(0)" ::: "memory");
    __builtin_amdgcn_sched_barrier(0);
    CONV(X1); MFMA_ALL(B1);

    // ---- write per-quarter partials (D layout: col=lane&15, row=(lane>>4)*4+reg) ----
    #pragma unroll
    for (int n = 0; n < 4; ++n)
        #pragma unroll
        for (int r = 0; r < 4; ++r)
            lg[w][g * 4 + r][n * 16 + rr] = acc[n][r];
    __syncthreads();

    // ---- top-2 per token: wave w -> tokens w*4..+3, lane = expert ----
    #pragma unroll 1
    for (int t = 0; t < 4; ++t) {
        const int tok = w * 4 + t;
        const float v = lg[0][tok][lane] + lg[1][tok][lane]
                      + lg[2][tok][lane] + lg[3][tok][lane];

        // top-1 (tie -> lower index, matching lax.top_k)
        float m1 = v; int i1 = lane;
        #pragma unroll
        for (int off = 32; off > 0; off >>= 1) {
            float ov = __shfl_xor(m1, off);
            int   oi = __shfl_xor(i1, off);
            if (ov > m1 || (ov == m1 && oi < i1)) { m1 = ov; i1 = oi; }
        }
        // top-2: mask out winner
        float m2 = (lane == i1) ? -INFINITY : v; int i2 = lane;
        #pragma unroll
        for (int off = 32; off > 0; off >>= 1) {
            float ov = __shfl_xor(m2, off);
            int   oi = __shfl_xor(i2, off);
            if (ov > m2 || (ov == m2 && oi < i2)) { m2 = ov; i2 = oi; }
        }

        if (lane == 0) {
            const int gtok = tok0 + tok;
            // softmax denom cancels: w1 = 1/(1+e^{l2-l1}), w2 = 1 - w1
            const float e  = expf(m2 - m1);
            const float w1 = 1.0f / (1.0f + e);
            const float w2 = e / (1.0f + e);
            out[gtok * 2 + 0] = (float)i1;
            out[gtok * 2 + 1] = (float)i2;
            out[NTOK * 2 + gtok * 2 + 0] = w1;
            out[NTOK * 2 + gtok * 2 + 1] = w2;
        }
    }
}

extern "C" void kernel_launch(void* const* d_in, const int* in_sizes, int n_in,
                              void* d_out, int out_size, void* d_ws, size_t ws_size,
                              hipStream_t stream) {
    const float* x  = (const float*)d_in[0];
    const float* Wg = (const float*)d_in[1];
    float* out = (float*)d_out;
    unsigned short* ws = (unsigned short*)d_ws;   // needs 768 KB
    // 1) split W into 3 bf16 planes (exact to ~2^-27)
    hipLaunchKernelGGL(wsplit_kernel, dim3(512), dim3(256), 0, stream, Wg, ws);
    // 2) MFMA router: 1024 blocks x 256 thr = 4096 waves (4/SIMD) for TLP
    hipLaunchKernelGGL(topk_router_kernel, dim3(NTOK / 16), dim3(256), 0, stream,
                       x, ws, out);
}

// Round 11
// 51.307 us; speedup vs baseline: 3.7058x; 3.7058x over previous
//
#include <hip/hip_runtime.h>
#include <math.h>

#define NTOK 16384
#define DK   2048
#define NEXP 64

typedef float f32x4 __attribute__((ext_vector_type(4)));
typedef int   i32x4 __attribute__((ext_vector_type(4)));
typedef short s16x8 __attribute__((ext_vector_type(8)));

// ---- scalar RTNE fp32->bf16 ----
__device__ __forceinline__ unsigned short f2bf(float f) {
    union { float f; unsigned u; } v; v.f = f;
    unsigned r = (v.u + 0x7FFFu + ((v.u >> 16) & 1u)) >> 16;
    return (unsigned short)r;
}
__device__ __forceinline__ float bf2f(unsigned short h) {
    union { unsigned u; float f; } v; v.u = ((unsigned)h) << 16;
    return v.f;
}

// Pre-kernel: 3-way bf16 split of W, PACKED in MFMA B-fragment order:
// ws[w][c][n][p][lane][8 shorts], lane = g*16 + rr holds expert 16n+rr,
// k = w*512 + c*32 + g*8 .. +8, plane p. A wave's per-round B-frag load is
// then 64 lanes x 16B CONTIGUOUS (1 KB) instead of a 16-line 4KB-stride gather
// (round-10 killer: address-bound + L2/L3 thrash, FETCH 263 MB).
__global__ __launch_bounds__(256) void wsplit_pack(const float* __restrict__ Wg,
                                                   unsigned short* __restrict__ ws) {
    const int t  = blockIdx.x * 256 + threadIdx.x;  // 16384 = 64 experts x 256 k-octets
    const int e  = t >> 8;          // expert 0..63
    const int k  = (t & 255) * 8;   // k-octet base
    const int w  = k >> 9;          // K-quarter
    const int c  = (k >> 5) & 15;   // round within quarter
    const int g  = (k >> 3) & 3;    // k-group within round
    const int rr = e & 15;
    const int n  = e >> 4;
    const int lane = g * 16 + rr;

    const float* src = Wg + (size_t)e * DK + k;
    unsigned short p0[8], p1[8], p2[8];
    #pragma unroll
    for (int j = 0; j < 8; ++j) {
        const float f = src[j];
        p0[j] = f2bf(f);  const float r1 = f - bf2f(p0[j]);
        p1[j] = f2bf(r1); const float r2 = r1 - bf2f(p1[j]);
        p2[j] = f2bf(r2);
    }
    const size_t base = ((((size_t)w * 16 + c) * 4 + n) * 3) * 512 + (size_t)lane * 8;
    *(s16x8*)(ws + base)        = *(s16x8*)p0;   // p=0
    *(s16x8*)(ws + base + 512)  = *(s16x8*)p1;   // p=1 (+64 lanes * 8)
    *(s16x8*)(ws + base + 1024) = *(s16x8*)p2;   // p=2
}

// packed fp32->bf16x2 (RTNE)
__device__ __forceinline__ unsigned cvtpk(float lo, float hi) {
    unsigned r;
    asm("v_cvt_pk_bf16_f32 %0, %1, %2" : "=v"(r) : "v"(lo), "v"(hi));
    return r;
}

// 3-way split of a float pair straight into A-fragment u32s (exact residuals).
#define SPLIT2(F0, F1, O0, O1, O2) { \
    const unsigned q0 = cvtpk((F0), (F1)); \
    const float s0 = (F0) - __builtin_bit_cast(float, q0 << 16); \
    const float s1 = (F1) - __builtin_bit_cast(float, q0 & 0xFFFF0000u); \
    const unsigned q1 = cvtpk(s0, s1); \
    const float t0 = s0 - __builtin_bit_cast(float, q1 << 16); \
    const float t1 = s1 - __builtin_bit_cast(float, q1 & 0xFFFF0000u); \
    O0 = (int)q0; O1 = (int)q1; O2 = (int)cvtpk(t0, t1); }

// Per round: 4 x-float4 + 12 packed-B i32x4 = 16 VMEM (the vmcnt unit).
#define ISSUE_X(XS, c) { \
    _Pragma("unroll") for (int m = 0; m < 2; ++m) \
        _Pragma("unroll") for (int h = 0; h < 2; ++h) \
            XS[m][h] = *(const float4*)(xbase + (size_t)m * 16 * DK + h * 4 + (c) * 32); }

#define ISSUE_B(BS, c) { \
    _Pragma("unroll") for (int n = 0; n < 4; ++n) \
        _Pragma("unroll") for (int p = 0; p < 3; ++p) \
            BS[n][p] = *(const i32x4*)(wbase + ((size_t)(c) * 12 + n * 3 + p) * 512); }

#define CONV1(XS, m) { \
    SPLIT2(XS[m][0].x, XS[m][0].y, A[m][0].x, A[m][1].x, A[m][2].x); \
    SPLIT2(XS[m][0].z, XS[m][0].w, A[m][0].y, A[m][1].y, A[m][2].y); \
    SPLIT2(XS[m][1].x, XS[m][1].y, A[m][0].z, A[m][1].z, A[m][2].z); \
    SPLIT2(XS[m][1].z, XS[m][1].w, A[m][0].w, A[m][1].w, A[m][2].w); }

#define MFMA_TERM(pa, pb, BS) { \
    _Pragma("unroll") for (int m = 0; m < 2; ++m) \
        _Pragma("unroll") for (int n = 0; n < 4; ++n) \
            acc[m][n] = __builtin_amdgcn_mfma_f32_16x16x32_bf16( \
                __builtin_bit_cast(s16x8, A[m][pa]), \
                __builtin_bit_cast(s16x8, BS[n][pb]), acc[m][n], 0, 0, 0); }

// 6 terms: (0,0),(0,1),(1,0),(1,1),(0,2),(2,0) -> logit exact to ~2^-24 rel
#define MFMA_ALL(BS) \
    MFMA_TERM(0, 0, BS) MFMA_TERM(0, 1, BS) MFMA_TERM(1, 0, BS) \
    MFMA_TERM(1, 1, BS) MFMA_TERM(0, 2, BS) MFMA_TERM(2, 0, BS)

// Steady phase: 32 VMEM outstanding (rounds c, c+1); vmcnt(16) lands round c.
#define PHASE_MAIN(XS, BS, c) { \
    asm volatile("s_waitcnt vmcnt(16)" ::: "memory"); \
    __builtin_amdgcn_sched_barrier(0); \
    CONV1(XS, 0); CONV1(XS, 1); \
    ISSUE_X(XS, (c) + 2); \
    MFMA_ALL(BS); \
    ISSUE_B(BS, (c) + 2); \
    __builtin_amdgcn_sched_barrier(0); }

__global__ __launch_bounds__(256, 2) void topk_router_kernel(
    const float* __restrict__ x,            // [NTOK][DK] fp32
    const unsigned short* __restrict__ ws,  // packed B frags (768 KB)
    float* __restrict__ out)                // [NTOK*2] idx (as float) ++ [NTOK*2] w
{
    __shared__ float lg[4][32][68];         // per-K-quarter partial logits

    const int tid  = threadIdx.x;
    const int w    = tid >> 6;              // wave 0..3 == K-quarter
    const int lane = tid & 63;
    const int rr   = lane & 15;
    const int g    = lane >> 4;
    const int tok0 = blockIdx.x * 32;

    // A-source: x[tok0 + rr + 16m][w*512 + c*32 + g*8 + 4h] (frag-layout-direct)
    const float* xbase = x + (size_t)(tok0 + rr) * DK + w * 512 + g * 8;
    // B-source: packed, this wave's K-quarter; per (c,n,p) 1 KB contiguous.
    const unsigned short* wbase = ws + (size_t)w * 98304 + (size_t)lane * 8;

    f32x4 acc[2][4];
    #pragma unroll
    for (int m = 0; m < 2; ++m)
        #pragma unroll
        for (int n = 0; n < 4; ++n) acc[m][n] = (f32x4){0.f, 0.f, 0.f, 0.f};

    float4 X0[2][2], X1[2][2];
    i32x4  B0[4][3], B1[4][3];
    i32x4  A[2][3];

    // ---- prologue: rounds 0,1 in flight ----
    ISSUE_X(X0, 0); ISSUE_B(B0, 0);
    ISSUE_X(X1, 1); ISSUE_B(B1, 1);

    // ---- main loop: 16 K32-rounds, no barriers, no LDS ----
    #pragma unroll 1
    for (int c = 0; c < 14; c += 2) {
        PHASE_MAIN(X0, B0, c);
        PHASE_MAIN(X1, B1, c + 1);
    }
    // tail rounds 14, 15
    asm volatile("s_waitcnt vmcnt(16)" ::: "memory");
    __builtin_amdgcn_sched_barrier(0);
    CONV1(X0, 0); CONV1(X0, 1); MFMA_ALL(B0);
    asm volatile("s_waitcnt vmcnt(0)" ::: "memory");
    __builtin_amdgcn_sched_barrier(0);
    CONV1(X1, 0); CONV1(X1, 1); MFMA_ALL(B1);

    // ---- per-quarter partials (D layout: col=lane&15, row=(lane>>4)*4+reg) ----
    #pragma unroll
    for (int m = 0; m < 2; ++m)
        #pragma unroll
        for (int n = 0; n < 4; ++n)
            #pragma unroll
            for (int r = 0; r < 4; ++r)
                lg[w][m * 16 + g * 4 + r][n * 16 + rr] = acc[m][n][r];
    __syncthreads();

    // ---- top-2 per token: wave w -> tokens w*8..+7, lane = expert ----
    #pragma unroll 1
    for (int t = 0; t < 8; ++t) {
        const int tok = w * 8 + t;
        const float v = lg[0][tok][lane] + lg[1][tok][lane]
                      + lg[2][tok][lane] + lg[3][tok][lane];

        // top-1 (tie -> lower index, matching lax.top_k)
        float m1 = v; int i1 = lane;
        #pragma unroll
        for (int off = 32; off > 0; off >>= 1) {
            float ov = __shfl_xor(m1, off);
            int   oi = __shfl_xor(i1, off);
            if (ov > m1 || (ov == m1 && oi < i1)) { m1 = ov; i1 = oi; }
        }
        // top-2: mask out winner
        float m2 = (lane == i1) ? -INFINITY : v; int i2 = lane;
        #pragma unroll
        for (int off = 32; off > 0; off >>= 1) {
            float ov = __shfl_xor(m2, off);
            int   oi = __shfl_xor(i2, off);
            if (ov > m2 || (ov == m2 && oi < i2)) { m2 = ov; i2 = oi; }
        }

        if (lane == 0) {
            const int gtok = tok0 + tok;
            // softmax denom cancels: w1 = 1/(1+e^{l2-l1}), w2 = 1 - w1
            const float e  = expf(m2 - m1);
            const float w1 = 1.0f / (1.0f + e);
            const float w2 = e / (1.0f + e);
            out[gtok * 2 + 0] = (float)i1;
            out[gtok * 2 + 1] = (float)i2;
            out[NTOK * 2 + gtok * 2 + 0] = w1;
            out[NTOK * 2 + gtok * 2 + 1] = w2;
        }
    }
}

extern "C" void kernel_launch(void* const* d_in, const int* in_sizes, int n_in,
                              void* d_out, int out_size, void* d_ws, size_t ws_size,
                              hipStream_t stream) {
    const float* x  = (const float*)d_in[0];
    const float* Wg = (const float*)d_in[1];
    float* out = (float*)d_out;
    unsigned short* ws = (unsigned short*)d_ws;   // 768 KB packed B
    // 1) split + pack W into MFMA-fragment order (one-time, ~5 us)
    hipLaunchKernelGGL(wsplit_pack, dim3(64), dim3(256), 0, stream, Wg, ws);
    // 2) MFMA router: 512 blocks x 256 thr = 2048 waves (2/SIMD), reg pipeline
    //    under the 256-VGPR cap of (256,2) -- round-10's spill was cap 128.
    hipLaunchKernelGGL(topk_router_kernel, dim3(NTOK / 32), dim3(256), 0, stream,
                       x, ws, out);
}

// Round 12
// 50.892 us; speedup vs baseline: 3.7360x; 1.0082x over previous
//
#include <hip/hip_runtime.h>
#include <math.h>

#define NTOK 16384
#define DK   2048
#define NEXP 64

typedef float f32x4 __attribute__((ext_vector_type(4)));
typedef int   i32x4 __attribute__((ext_vector_type(4)));
typedef short s16x8 __attribute__((ext_vector_type(8)));

// ---- scalar RTNE fp32->bf16 ----
__device__ __forceinline__ unsigned short f2bf(float f) {
    union { float f; unsigned u; } v; v.f = f;
    unsigned r = (v.u + 0x7FFFu + ((v.u >> 16) & 1u)) >> 16;
    return (unsigned short)r;
}
__device__ __forceinline__ float bf2f(unsigned short h) {
    union { unsigned u; float f; } v; v.u = ((unsigned)h) << 16;
    return v.f;
}

// Pre-kernel: 3-way bf16 split of W, PACKED in MFMA B-fragment order:
// ws[w][c][n][p][lane][8 shorts], lane = g*16 + rr holds expert 16n+rr,
// k = w*512 + c*32 + g*8 .. +8, plane p. Per-round B-frag load = 1 KB
// contiguous per (c,n,p) -> coalesced + L2-prefetch friendly.
__global__ __launch_bounds__(256) void wsplit_pack(const float* __restrict__ Wg,
                                                   unsigned short* __restrict__ ws) {
    const int t  = blockIdx.x * 256 + threadIdx.x;  // 16384 = 64 experts x 256 k-octets
    const int e  = t >> 8;          // expert 0..63
    const int k  = (t & 255) * 8;   // k-octet base
    const int w  = k >> 9;          // K-quarter
    const int c  = (k >> 5) & 15;   // round within quarter
    const int g  = (k >> 3) & 3;    // k-group within round
    const int rr = e & 15;
    const int n  = e >> 4;
    const int lane = g * 16 + rr;

    const float* src = Wg + (size_t)e * DK + k;
    unsigned short p0[8], p1[8], p2[8];
    #pragma unroll
    for (int j = 0; j < 8; ++j) {
        const float f = src[j];
        p0[j] = f2bf(f);  const float r1 = f - bf2f(p0[j]);
        p1[j] = f2bf(r1); const float r2 = r1 - bf2f(p1[j]);
        p2[j] = f2bf(r2);
    }
    const size_t base = ((((size_t)w * 16 + c) * 4 + n) * 3) * 512 + (size_t)lane * 8;
    *(s16x8*)(ws + base)        = *(s16x8*)p0;   // p=0
    *(s16x8*)(ws + base + 512)  = *(s16x8*)p1;   // p=1
    *(s16x8*)(ws + base + 1024) = *(s16x8*)p2;   // p=2
}

// packed fp32->bf16x2 (RTNE)
__device__ __forceinline__ unsigned cvtpk(float lo, float hi) {
    unsigned r;
    asm("v_cvt_pk_bf16_f32 %0, %1, %2" : "=v"(r) : "v"(lo), "v"(hi));
    return r;
}

// 3-way split of a float pair straight into A-fragment u32s (exact residuals).
#define SPLIT2(F0, F1, O0, O1, O2) { \
    const unsigned q0 = cvtpk((F0), (F1)); \
    const float s0 = (F0) - __builtin_bit_cast(float, q0 << 16); \
    const float s1 = (F1) - __builtin_bit_cast(float, q0 & 0xFFFF0000u); \
    const unsigned q1 = cvtpk(s0, s1); \
    const float t0 = s0 - __builtin_bit_cast(float, q1 << 16); \
    const float t1 = s1 - __builtin_bit_cast(float, q1 & 0xFFFF0000u); \
    O0 = (int)q0; O1 = (int)q1; O2 = (int)cvtpk(t0, t1); }

// Per round: 4 x-float4 + 12 packed-B i32x4 = 16 VMEM (the vmcnt unit).
#define ISSUE_X(XS, c) { \
    _Pragma("unroll") for (int m = 0; m < 2; ++m) \
        _Pragma("unroll") for (int h = 0; h < 2; ++h) \
            XS[m][h] = *(const float4*)(xbase + (size_t)m * 16 * DK + h * 4 + (c) * 32); }

#define ISSUE_B(BS, c) { \
    _Pragma("unroll") for (int n = 0; n < 4; ++n) \
        _Pragma("unroll") for (int p = 0; p < 3; ++p) \
            BS[n][p] = *(const i32x4*)(wbase + ((size_t)(c) * 12 + n * 3 + p) * 512); }

#define CONV1(XS, m) { \
    SPLIT2(XS[m][0].x, XS[m][0].y, A[m][0].x, A[m][1].x, A[m][2].x); \
    SPLIT2(XS[m][0].z, XS[m][0].w, A[m][0].y, A[m][1].y, A[m][2].y); \
    SPLIT2(XS[m][1].x, XS[m][1].y, A[m][0].z, A[m][1].z, A[m][2].z); \
    SPLIT2(XS[m][1].z, XS[m][1].w, A[m][0].w, A[m][1].w, A[m][2].w); }

#define MFMA_TERM(pa, pb, BS) { \
    _Pragma("unroll") for (int m = 0; m < 2; ++m) \
        _Pragma("unroll") for (int n = 0; n < 4; ++n) \
            acc[m][n] = __builtin_amdgcn_mfma_f32_16x16x32_bf16( \
                __builtin_bit_cast(s16x8, A[m][pa]), \
                __builtin_bit_cast(s16x8, BS[n][pb]), acc[m][n], 0, 0, 0); }

// 6 terms: (0,0),(0,1),(1,0),(1,1),(0,2),(2,0) -> logit exact to ~2^-24 rel
#define MFMA_ALL(BS) \
    MFMA_TERM(0, 0, BS) MFMA_TERM(0, 1, BS) MFMA_TERM(1, 0, BS) \
    MFMA_TERM(1, 1, BS) MFMA_TERM(0, 2, BS) MFMA_TERM(2, 0, BS)

// Steady phase (rounds 0..11): 48 VMEM outstanding (c, c+1, c+2); vmcnt(32)
// lands round c; refill buffer with round c+3.
#define PHASE(XS, BS, c, NCNT, DO_ISSUE) { \
    asm volatile("s_waitcnt vmcnt(" #NCNT ")" ::: "memory"); \
    __builtin_amdgcn_sched_barrier(0); \
    CONV1(XS, 0); CONV1(XS, 1); \
    MFMA_ALL(BS); \
    if (DO_ISSUE) { ISSUE_X(XS, (c) + 3); ISSUE_B(BS, (c) + 3); } \
    __builtin_amdgcn_sched_barrier(0); }

__global__ __launch_bounds__(256, 2) void topk_router_kernel(
    const float* __restrict__ x,            // [NTOK][DK] fp32
    const unsigned short* __restrict__ ws,  // packed B frags (768 KB)
    float* __restrict__ out)                // [NTOK*2] idx (as float) ++ [NTOK*2] w
{
    __shared__ float lg[4][32][68];         // per-K-quarter partial logits

    const int tid  = threadIdx.x;
    const int w    = tid >> 6;              // wave 0..3 == K-quarter
    const int lane = tid & 63;
    const int rr   = lane & 15;
    const int g    = lane >> 4;
    const int tok0 = blockIdx.x * 32;

    // A-source: x[tok0 + rr + 16m][w*512 + c*32 + g*8 + 4h] (frag-layout-direct)
    const float* xbase = x + (size_t)(tok0 + rr) * DK + w * 512 + g * 8;
    // B-source: packed, this wave's K-quarter; per (c,n,p) 1 KB contiguous.
    const unsigned short* wbase = ws + (size_t)w * 98304 + (size_t)lane * 8;

    f32x4 acc[2][4];
    #pragma unroll
    for (int m = 0; m < 2; ++m)
        #pragma unroll
        for (int n = 0; n < 4; ++n) acc[m][n] = (f32x4){0.f, 0.f, 0.f, 0.f};

    float4 X0[2][2], X1[2][2], X2[2][2];
    i32x4  B0[4][3], B1[4][3], B2[4][3];
    i32x4  A[2][3];

    // ---- prologue: rounds 0,1,2 in flight (16 VMEM each) ----
    ISSUE_X(X0, 0); ISSUE_B(B0, 0);
    ISSUE_X(X1, 1); ISSUE_B(B1, 1);
    ISSUE_X(X2, 2); ISSUE_B(B2, 2);

    // ---- main: rounds 0..11, 3-deep, vmcnt(32); issues rounds 3..14 ----
    #pragma unroll 1
    for (int c = 0; c < 12; c += 3) {
        PHASE(X0, B0, c + 0, 32, 1);
        PHASE(X1, B1, c + 1, 32, 1);
        PHASE(X2, B2, c + 2, 32, 1);
    }
    // ---- exact-counted tail: rounds 12..15 ----
    PHASE(X0, B0, 12, 32, 1);   // issues round 15 (into buf0)
    PHASE(X1, B1, 13, 32, 0);   // outstanding 14,15 = 32
    PHASE(X2, B2, 14, 16, 0);   // outstanding 15 = 16
    PHASE(X0, B0, 15,  0, 0);   // drain

    // ---- per-quarter partials (D layout: col=lane&15, row=(lane>>4)*4+reg) ----
    #pragma unroll
    for (int m = 0; m < 2; ++m)
        #pragma unroll
        for (int n = 0; n < 4; ++n)
            #pragma unroll
            for (int r = 0; r < 4; ++r)
                lg[w][m * 16 + g * 4 + r][n * 16 + rr] = acc[m][n][r];
    __syncthreads();

    // ---- top-2 per token: wave w -> tokens w*8..+7, lane = expert ----
    #pragma unroll 1
    for (int t = 0; t < 8; ++t) {
        const int tok = w * 8 + t;
        const float v = lg[0][tok][lane] + lg[1][tok][lane]
                      + lg[2][tok][lane] + lg[3][tok][lane];

        // top-1 (tie -> lower index, matching lax.top_k)
        float m1 = v; int i1 = lane;
        #pragma unroll
        for (int off = 32; off > 0; off >>= 1) {
            float ov = __shfl_xor(m1, off);
            int   oi = __shfl_xor(i1, off);
            if (ov > m1 || (ov == m1 && oi < i1)) { m1 = ov; i1 = oi; }
        }
        // top-2: mask out winner
        float m2 = (lane == i1) ? -INFINITY : v; int i2 = lane;
        #pragma unroll
        for (int off = 32; off > 0; off >>= 1) {
            float ov = __shfl_xor(m2, off);
            int   oi = __shfl_xor(i2, off);
            if (ov > m2 || (ov == m2 && oi < i2)) { m2 = ov; i2 = oi; }
        }

        if (lane == 0) {
            const int gtok = tok0 + tok;
            // softmax denom cancels: w1 = 1/(1+e^{l2-l1}), w2 = 1 - w1
            const float e  = expf(m2 - m1);
            const float w1 = 1.0f / (1.0f + e);
            const float w2 = e / (1.0f + e);
            out[gtok * 2 + 0] = (float)i1;
            out[gtok * 2 + 1] = (float)i2;
            out[NTOK * 2 + gtok * 2 + 0] = w1;
            out[NTOK * 2 + gtok * 2 + 1] = w2;
        }
    }
}

extern "C" void kernel_launch(void* const* d_in, const int* in_sizes, int n_in,
                              void* d_out, int out_size, void* d_ws, size_t ws_size,
                              hipStream_t stream) {
    const float* x  = (const float*)d_in[0];
    const float* Wg = (const float*)d_in[1];
    float* out = (float*)d_out;
    unsigned short* ws = (unsigned short*)d_ws;   // 768 KB packed B
    // 1) split + pack W into MFMA-fragment order (one-time)
    hipLaunchKernelGGL(wsplit_pack, dim3(64), dim3(256), 0, stream, Wg, ws);
    // 2) MFMA router: 512 blocks x 256 thr = 2048 waves (2/SIMD), 3-deep
    //    register pipeline (48 VMEM in flight) under the 256-VGPR cap.
    hipLaunchKernelGGL(topk_router_kernel, dim3(NTOK / 32), dim3(256), 0, stream,
                       x, ws, out);
}